// Round 1
// baseline (20586.092 us; speedup 1.0000x reference)
//
#include <hip/hip_runtime.h>
#include <cstdint>
#include <cstddef>

// Problem dims
#define V   32000
#define E   64
#define H   128
#define S   1024
#define B   128
#define T   64
#define H3  384   // 3*H

// ws layout (float offsets)
static const size_t OFF_ENC   = 0;                       // enc_out [S][B][H]   16,777,216 f
static const size_t OFF_WE    = OFF_ENC  + (size_t)S*B*H;          // We_pre  16,777,216 f
static const size_t OFF_WT    = OFF_WE   + (size_t)S*B*H;          // out_W^T [256][32000] 8,192,000 f
static const size_t OFF_H     = OFF_WT   + (size_t)256*V;          // h [B][H]
static const size_t OFF_X     = OFF_H    + (size_t)B*H;            // X = [h2|ctx] [B][256]
static const size_t OFF_WIHT  = OFF_X    + (size_t)B*256;          // dec_Wih^T [192][384]
static const size_t OFF_WHHT  = OFF_WIHT + (size_t)192*H3;         // dec_Whh^T [128][384]
static const size_t OFF_WATD  = OFF_WHHT + (size_t)H*H3;           // attn_W[:, :H]^T [128][128]
static const size_t OFF_WAET  = OFF_WATD + (size_t)H*H;            // attn_W[:, H:]^T [128][128]
static const size_t OFF_SLOTS = OFF_WAET + (size_t)H*H;            // 128 u64 argmax slots

__device__ __forceinline__ float fast_sigmoid(float x) {
    float e = __expf(-x);
    return 1.0f / (1.0f + e);
}
__device__ __forceinline__ float fast_tanh(float x) {
    x = fminf(fmaxf(x, -15.f), 15.f);
    float e = __expf(2.f * x);
    return (e - 1.f) / (e + 1.f);
}

// ---------------- one-time transposes ----------------
__global__ void k_setup(const float* __restrict__ out_W,
                        const float* __restrict__ dec_Wih,
                        const float* __restrict__ dec_Whh,
                        const float* __restrict__ attn_W,
                        float* __restrict__ WT,
                        float* __restrict__ WihT,
                        float* __restrict__ WhhT,
                        float* __restrict__ WaTd,
                        float* __restrict__ WaeT)
{
    int blk = blockIdx.x, t = threadIdx.x;
    if (blk < 2000) {
        __shared__ float tl[64][65];
        int bc = blk >> 2, bk = blk & 3;   // c-tile, k-tile
        #pragma unroll
        for (int i = 0; i < 16; ++i) {
            int flat = t + 256 * i;
            int r = flat >> 6, c = flat & 63;
            tl[r][c] = out_W[(size_t)(bc * 64 + r) * 256 + bk * 64 + c];
        }
        __syncthreads();
        #pragma unroll
        for (int i = 0; i < 16; ++i) {
            int flat = t + 256 * i;
            int r = flat >> 6, c = flat & 63;
            WT[(size_t)(bk * 64 + r) * V + bc * 64 + c] = tl[c][r];
        }
    } else if (blk == 2000) {
        for (int idx = t; idx < H3 * 192; idx += 256) {
            int j = idx / 192, e = idx % 192;
            WihT[e * H3 + j] = dec_Wih[idx];
        }
    } else if (blk == 2001) {
        for (int idx = t; idx < H3 * H; idx += 256) {
            int j = idx >> 7, k = idx & 127;
            WhhT[k * H3 + j] = dec_Whh[idx];
        }
    } else {
        for (int idx = t; idx < H * H; idx += 256) {
            int hh = idx >> 7, k = idx & 127;
            WaTd[k * H + hh] = attn_W[hh * 256 + k];
            WaeT[k * H + hh] = attn_W[hh * 256 + 128 + k];
        }
    }
}

// ---------------- encoder scan: 1 block per batch row ----------------
__global__ __launch_bounds__(384, 2)
void k_encoder(const int* __restrict__ seq,
               const float* __restrict__ emb_table,
               const float* __restrict__ Wih,
               const float* __restrict__ Whh,
               const float* __restrict__ bih,
               const float* __restrict__ bhh,
               float* __restrict__ enc_out,
               float* __restrict__ h_out)
{
    int b = blockIdx.x, j = threadIdx.x;
    __shared__ __align__(16) float4 s_emb[2][16];
    __shared__ __align__(16) float4 s_h4[32];
    __shared__ float s_rz[256];
    __shared__ float s_gn[128];
    __shared__ float s_hn[128];
    __shared__ int   s_seq[S];
    float* s_h = (float*)s_h4;

    // weights in VGPRs: thread j owns gate row j
    float4 wih[16], whh[32];
    const float4* pwi = (const float4*)(Wih + (size_t)j * 64);
    #pragma unroll
    for (int i = 0; i < 16; ++i) wih[i] = pwi[i];
    const float4* pwh = (const float4*)(Whh + (size_t)j * 128);
    #pragma unroll
    for (int i = 0; i < 32; ++i) whh[i] = pwh[i];
    float bi = bih[j], bh = bhh[j];

    for (int s = j; s < S; s += 384) s_seq[s] = seq[s * B + b];
    if (j < 32) s_h4[j] = make_float4(0.f, 0.f, 0.f, 0.f);
    __syncthreads();
    if (j < 16) s_emb[0][j] = ((const float4*)emb_table)[(size_t)s_seq[0] * 16 + j];
    __syncthreads();

    for (int s = 0; s < S; ++s) {
        int cur = s & 1;
        // prefetch next embedding row
        float4 pf;
        bool do_pf = (j >= 368) && (s < S - 1);
        if (do_pf) pf = ((const float4*)emb_table)[(size_t)s_seq[s + 1] * 16 + (j - 368)];

        float a0 = 0.f, a1 = 0.f, a2 = 0.f, a3 = 0.f;
        #pragma unroll
        for (int i = 0; i < 16; ++i) {
            float4 e4 = s_emb[cur][i];
            a0 = fmaf(e4.x, wih[i].x, a0);
            a1 = fmaf(e4.y, wih[i].y, a1);
            a2 = fmaf(e4.z, wih[i].z, a2);
            a3 = fmaf(e4.w, wih[i].w, a3);
        }
        float gi = bi + ((a0 + a1) + (a2 + a3));

        float c0 = 0.f, c1 = 0.f, c2 = 0.f, c3 = 0.f;
        #pragma unroll
        for (int i = 0; i < 32; ++i) {
            float4 h4 = s_h4[i];
            c0 = fmaf(h4.x, whh[i].x, c0);
            c1 = fmaf(h4.y, whh[i].y, c1);
            c2 = fmaf(h4.z, whh[i].z, c2);
            c3 = fmaf(h4.w, whh[i].w, c3);
        }
        float gh = bh + ((c0 + c1) + (c2 + c3));

        if (do_pf) s_emb[1 - cur][j - 368] = pf;

        if (j < 256) s_rz[j] = fast_sigmoid(gi + gh);   // r (j<128), z (128..255)
        else { s_gn[j - 256] = gi; s_hn[j - 256] = gh; } // n-gate parts
        __syncthreads();

        if (j < 128) {
            float r = s_rz[j], z = s_rz[128 + j];
            float n = fast_tanh(s_gn[j] + r * s_hn[j]);
            float hn = (1.f - z) * n + z * s_h[j];
            s_h[j] = hn;
            enc_out[((size_t)s * B + b) * H + j] = hn;
        }
        __syncthreads();
    }
    if (j < 128) h_out[b * H + j] = s_h[j];
}

// ---------------- We_pre = enc_out @ attn_W[:,H:]^T + attn_b ----------------
__global__ void k_wepre(const float* __restrict__ enc_out,
                        const float* __restrict__ WaeT,
                        const float* __restrict__ attn_b,
                        float* __restrict__ We)
{
    __shared__ float xs[16][128];
    int r0 = blockIdx.x * 16;
    int t = threadIdx.x;
    #pragma unroll
    for (int i = 0; i < 8; ++i) {
        int flat = t + 256 * i;
        int rr = flat >> 7, c = flat & 127;
        xs[rr][c] = enc_out[(size_t)(r0 + rr) * H + c];
    }
    __syncthreads();
    int hh = t & 127, rh = t >> 7;
    float acc[8];
    #pragma unroll
    for (int i = 0; i < 8; ++i) acc[i] = 0.f;
    for (int k = 0; k < 128; ++k) {
        float w = WaeT[k * H + hh];
        #pragma unroll
        for (int i = 0; i < 8; ++i)
            acc[i] = fmaf(xs[rh * 8 + i][k], w, acc[i]);
    }
    float bb = attn_b[hh];
    #pragma unroll
    for (int i = 0; i < 8; ++i)
        We[(size_t)(r0 + rh * 8 + i) * H + hh] = acc[i] + bb;
}

// ---------------- per decode step: attention + softmax + context + GRU ----------------
__global__ __launch_bounds__(512, 1)
void k_attn(const int* __restrict__ seq,
            const float* __restrict__ emb_table,
            const float* __restrict__ enc_out,
            const float* __restrict__ We,
            const float* __restrict__ WaTd,
            const float* __restrict__ attn_v,
            const float* __restrict__ WihT,
            const float* __restrict__ WhhT,
            const float* __restrict__ dbih,
            const float* __restrict__ dbhh,
            float* __restrict__ h_buf,
            float* __restrict__ X,
            unsigned long long* __restrict__ slots,
            int step)
{
    int b = blockIdx.x, t = threadIdx.x;
    __shared__ __align__(16) float sUh[128];
    __shared__ float sSc[S];
    __shared__ float sCtx[128];
    __shared__ __align__(16) float sEmb[64];
    __shared__ float sH[128];
    __shared__ float sRz[256];
    __shared__ float sGn[128];
    __shared__ float sHn[128];
    __shared__ float sRed[512];
    __shared__ float sC4[4][128];
    __shared__ int sTok;

    if (t < 128) sH[t] = h_buf[b * H + t];
    if (t == 0) {
        int tok;
        if (step == 0) tok = seq[b];                       // seq[0, b]
        else {
            unsigned long long kk = slots[b];
            tok = (int)(0xFFFFFFFFu - (unsigned)(kk & 0xFFFFFFFFull));
        }
        slots[b] = 0ull;                                   // reset for this step's proj
        sTok = tok;
    }
    __syncthreads();
    if (t < 16) ((float4*)sEmb)[t] = ((const float4*)emb_table)[(size_t)sTok * 16 + t];
    if (t < 128) {
        float acc = 0.f;
        for (int k = 0; k < 128; ++k)
            acc = fmaf(sH[k], WaTd[k * H + t], acc);
        sUh[t] = acc;                                      // attn_b folded into We
    }
    __syncthreads();

    // scores: one wave per s
    {
        int w = t >> 6, l = t & 63;
        float2 uh2 = ((float2*)sUh)[l];
        float2 v2  = ((const float2*)attn_v)[l];
        for (int s = w; s < S; s += 8) {
            float2 we2 = ((const float2*)We)[((size_t)s * B + b) * 64 + l];
            float val = v2.x * fast_tanh(uh2.x + we2.x)
                      + v2.y * fast_tanh(uh2.y + we2.y);
            #pragma unroll
            for (int off = 1; off < 64; off <<= 1)
                val += __shfl_xor(val, off);
            if (l == 0) sSc[s] = val;
        }
    }
    __syncthreads();

    // softmax: max
    sRed[t] = fmaxf(sSc[t], sSc[t + 512]);
    __syncthreads();
    for (int st = 256; st >= 1; st >>= 1) {
        if (t < st) sRed[t] = fmaxf(sRed[t], sRed[t + st]);
        __syncthreads();
    }
    float M = sRed[0];
    __syncthreads();
    // exp + sum
    {
        float e0 = __expf(sSc[t] - M);
        float e1 = __expf(sSc[t + 512] - M);
        sSc[t] = e0; sSc[t + 512] = e1;
        sRed[t] = e0 + e1;
    }
    __syncthreads();
    for (int st = 256; st >= 1; st >>= 1) {
        if (t < st) sRed[t] += sRed[t + st];
        __syncthreads();
    }
    float SUM = sRed[0];

    // context accumulation
    {
        int hh = t & 127, q = t >> 7;
        float acc = 0.f;
        for (int s = q; s < S; s += 4)
            acc = fmaf(sSc[s], enc_out[((size_t)s * B + b) * H + hh], acc);
        sC4[q][hh] = acc;
    }
    __syncthreads();
    if (t < 128)
        sCtx[t] = ((sC4[0][t] + sC4[1][t]) + (sC4[2][t] + sC4[3][t])) / SUM;
    __syncthreads();

    // decoder GRU gates
    if (t < H3) {
        int j = t;
        float gi = dbih[j];
        for (int e = 0; e < 64; ++e)
            gi = fmaf(sEmb[e], WihT[e * H3 + j], gi);
        for (int k = 0; k < 128; ++k)
            gi = fmaf(sCtx[k], WihT[(64 + k) * H3 + j], gi);
        float gh = dbhh[j];
        for (int k = 0; k < 128; ++k)
            gh = fmaf(sH[k], WhhT[k * H3 + j], gh);
        if (j < 256) sRz[j] = fast_sigmoid(gi + gh);
        else { sGn[j - 256] = gi; sHn[j - 256] = gh; }
    }
    __syncthreads();
    if (t < 128) {
        float r = sRz[t], z = sRz[128 + t];
        float n = fast_tanh(sGn[t] + r * sHn[t]);
        float h2 = (1.f - z) * n + z * sH[t];
        h_buf[b * H + t] = h2;
        X[b * 256 + t] = h2;
        X[b * 256 + 128 + t] = sCtx[t];
    }
}

// ---------------- logit projection + fused argmax ----------------
__global__ __launch_bounds__(256, 2)
void k_proj(const float* __restrict__ X,
            const float* __restrict__ WT,
            const float* __restrict__ out_b,
            float* __restrict__ out,
            unsigned long long* __restrict__ slots,
            int step)
{
    __shared__ __align__(16) float4 sX[32][65];
    int cb = blockIdx.x;           // 0..124 -> 256 cols each
    int rq = blockIdx.y;           // 0..3   -> 32 rows each
    int t = threadIdx.x;
    int c0 = cb * 256, r0 = rq * 32;

    #pragma unroll
    for (int i = 0; i < 8; ++i) {
        int flat = t + 256 * i;            // 0..2047
        int r = flat >> 6, c4 = flat & 63;
        sX[r][c4] = ((const float4*)X)[(size_t)(r0 + r) * 64 + c4];
    }
    __syncthreads();

    int cg = t & 31, rg = t >> 5;
    int cl = cg * 8, rl = rg * 4;
    float acc[4][8];
    #pragma unroll
    for (int i = 0; i < 4; ++i)
        #pragma unroll
        for (int jj = 0; jj < 8; ++jj) acc[i][jj] = 0.f;

    const float4* WT4 = (const float4*)WT;
    size_t wbase = (size_t)(c0 + cl) / 4;
    for (int kk = 0; kk < 256; kk += 4) {
        float4 xa[4];
        #pragma unroll
        for (int i = 0; i < 4; ++i) xa[i] = sX[rl + i][kk >> 2];
        #pragma unroll
        for (int d = 0; d < 4; ++d) {
            float4 w0 = WT4[(size_t)(kk + d) * (V / 4) + wbase];
            float4 w1 = WT4[(size_t)(kk + d) * (V / 4) + wbase + 1];
            #pragma unroll
            for (int i = 0; i < 4; ++i) {
                float xv = (d == 0) ? xa[i].x : (d == 1) ? xa[i].y : (d == 2) ? xa[i].z : xa[i].w;
                acc[i][0] = fmaf(xv, w0.x, acc[i][0]);
                acc[i][1] = fmaf(xv, w0.y, acc[i][1]);
                acc[i][2] = fmaf(xv, w0.z, acc[i][2]);
                acc[i][3] = fmaf(xv, w0.w, acc[i][3]);
                acc[i][4] = fmaf(xv, w1.x, acc[i][4]);
                acc[i][5] = fmaf(xv, w1.y, acc[i][5]);
                acc[i][6] = fmaf(xv, w1.z, acc[i][6]);
                acc[i][7] = fmaf(xv, w1.w, acc[i][7]);
            }
        }
    }

    float4 b0 = ((const float4*)out_b)[(c0 + cl) / 4];
    float4 b1 = ((const float4*)out_b)[(c0 + cl) / 4 + 1];
    unsigned long long bestkey[4];
    #pragma unroll
    for (int i = 0; i < 4; ++i) {
        float vals[8];
        vals[0] = acc[i][0] + b0.x; vals[1] = acc[i][1] + b0.y;
        vals[2] = acc[i][2] + b0.z; vals[3] = acc[i][3] + b0.w;
        vals[4] = acc[i][4] + b1.x; vals[5] = acc[i][5] + b1.y;
        vals[6] = acc[i][6] + b1.z; vals[7] = acc[i][7] + b1.w;
        size_t base = ((size_t)step * B + r0 + rl + i) * V + c0 + cl;
        float4 o0 = make_float4(vals[0], vals[1], vals[2], vals[3]);
        float4 o1 = make_float4(vals[4], vals[5], vals[6], vals[7]);
        *(float4*)(out + base) = o0;
        *(float4*)(out + base + 4) = o1;
        // local argmax (first-max tie-break)
        float bv = vals[0]; int bc = 0;
        #pragma unroll
        for (int jj = 1; jj < 8; ++jj)
            if (vals[jj] > bv) { bv = vals[jj]; bc = jj; }
        unsigned u = __float_as_uint(bv);
        unsigned m = (u & 0x80000000u) ? ~u : (u | 0x80000000u);   // order-preserving
        unsigned col = (unsigned)(c0 + cl + bc);
        bestkey[i] = ((unsigned long long)m << 32) | (unsigned long long)(0xFFFFFFFFu - col);
    }
    // reduce across the 32 col-groups (within each 32-lane half)
    #pragma unroll
    for (int off = 1; off < 32; off <<= 1) {
        #pragma unroll
        for (int i = 0; i < 4; ++i) {
            unsigned long long o = __shfl_xor(bestkey[i], off);
            if (o > bestkey[i]) bestkey[i] = o;
        }
    }
    if (cg == 0) {
        #pragma unroll
        for (int i = 0; i < 4; ++i)
            atomicMax(&slots[r0 + rl + i], bestkey[i]);
    }
}

extern "C" void kernel_launch(void* const* d_in, const int* in_sizes, int n_in,
                              void* d_out, int out_size, void* d_ws, size_t ws_size,
                              hipStream_t stream)
{
    const int*   seq  = (const int*)d_in[0];
    const float* emb  = (const float*)d_in[2];
    const float* eWih = (const float*)d_in[3];
    const float* eWhh = (const float*)d_in[4];
    const float* ebih = (const float*)d_in[5];
    const float* ebhh = (const float*)d_in[6];
    const float* attW = (const float*)d_in[7];
    const float* attb = (const float*)d_in[8];
    const float* attv = (const float*)d_in[9];
    const float* dWih = (const float*)d_in[10];
    const float* dWhh = (const float*)d_in[11];
    const float* dbih = (const float*)d_in[12];
    const float* dbhh = (const float*)d_in[13];
    const float* outW = (const float*)d_in[14];
    const float* outb = (const float*)d_in[15];
    float* out = (float*)d_out;
    float* ws  = (float*)d_ws;

    float* enc_o = ws + OFF_ENC;
    float* We    = ws + OFF_WE;
    float* WT    = ws + OFF_WT;
    float* hbuf  = ws + OFF_H;
    float* Xb    = ws + OFF_X;
    float* WihT  = ws + OFF_WIHT;
    float* WhhT  = ws + OFF_WHHT;
    float* WaTd  = ws + OFF_WATD;
    float* WaeT  = ws + OFF_WAET;
    unsigned long long* slots = (unsigned long long*)(ws + OFF_SLOTS);

    k_setup<<<2003, 256, 0, stream>>>(outW, dWih, dWhh, attW, WT, WihT, WhhT, WaTd, WaeT);
    k_encoder<<<B, 384, 0, stream>>>(seq, emb, eWih, eWhh, ebih, ebhh, enc_o, hbuf);
    k_wepre<<<(S * B) / 16, 256, 0, stream>>>(enc_o, WaeT, attb, We);
    for (int t = 0; t < T; ++t) {
        k_attn<<<B, 512, 0, stream>>>(seq, emb, enc_o, We, WaTd, attv,
                                      WihT, WhhT, dbih, dbhh, hbuf, Xb, slots, t);
        k_proj<<<dim3(125, 4), 256, 0, stream>>>(Xb, WT, outb, out, slots, t);
    }
}